// Round 3
// 259.073 us; speedup vs baseline: 1.0213x; 1.0213x over previous
//
#include <hip/hip_runtime.h>
#include <math.h>

#define WW 1024
#define HH 1024
#define TI 64          // output tile extent in i (x)
#define TJ 128         // output tile extent in j (y)
#define HALO_J 148     // hc (y) extent = TJ + 20
#define VALID_I 84     // valid hr (x) extent = TI + 20
#define FILL_I 96      // filled hr extent (chunks read up to x=96; [84,96) zero)
#define PITCH_T 104    // ThT row pitch in elems; 208B row, 52 dwords == 20 mod 32
#define AOFF 448       // float offset of A-pattern table in ws

typedef short short8 __attribute__((ext_vector_type(8)));
typedef float float16 __attribute__((ext_vector_type(16)));

__device__ __forceinline__ unsigned short f2bf(float f) {
    union { float f; unsigned int u; } c; c.f = f;
    unsigned int u = c.u;
    return (unsigned short)((u + 0x7FFFu + ((u >> 16) & 1u)) >> 16);
}

// ---------------- prep: PSF normalize, params, Toeplitz A-pattern table ------
// A-pattern: for chunk-offset d in [0,4), lane l (m=l&31, k0=8*(l>>5)),
//   Apat[v][d][l][q] = P_bf16[16d + k0 + q - m][v]   (0 if u outside [0,20])
// Note: independent of the mq output-block (chunk index 2*mq+d shifts B, not A).
__global__ void prep_kernel(const float* __restrict__ raw_psf,
                            const float* __restrict__ x0p, const float* __restrict__ y0p,
                            const float* __restrict__ raw_b, const float* __restrict__ raw_rc,
                            const float* __restrict__ raw_sub,
                            float* __restrict__ ws) {
    __shared__ float red[512];
    __shared__ float psn[441];
    int t = threadIdx.x;
    float v = 0.f;
    if (t < 441) v = fmaxf(raw_psf[t], 0.f);
    red[t] = v;
    __syncthreads();
    for (int s = 256; s > 0; s >>= 1) {
        if (t < s) red[t] += red[t + s];
        __syncthreads();
    }
    float sum = fmaxf(red[0], 1e-12f);
    if (t < 441) { float pn = v / sum; ws[t] = pn; psn[t] = pn; }
    if (t == 0) {
        float b  = log1pf(expf(raw_b[0]))  + 1e-8f;
        float rc = log1pf(expf(raw_rc[0])) + 1e-8f;
        ws[441] = b;
        ws[442] = 1e-12f + rc * rc;
        ws[443] = 0.25f * tanhf(raw_sub[0]);
        ws[444] = 0.25f * tanhf(raw_sub[1]);
        ws[445] = x0p[0];
        ws[446] = y0p[0];
    }
    __syncthreads();

    short* A = (short*)(ws + AOFF);
    for (int g = t; g < 21 * 256; g += 512) {      // g = v*256 + d*64 + l
        int vv = g >> 8;
        int r  = g & 255;
        int d  = r >> 6;
        int l  = r & 63;
        int m  = l & 31;
        int k0 = (l >> 5) << 3;
        short8 o8;
#pragma unroll
        for (int q = 0; q < 8; ++q) {
            int u = 16 * d + k0 + q - m;
            unsigned short pv = 0;
            if ((unsigned)u <= 20u) pv = f2bf(psn[u * 21 + vv]);
            o8[q] = (short)pv;
        }
        *(short8*)&A[(size_t)g * 8] = o8;
    }
}

// ---------------- fused: bilinear warp -> bf16 LDS (transposed) -> MFMA conv -
__global__ __launch_bounds__(256, 4) void fused_kernel(
        const float* __restrict__ src, const float* __restrict__ pp,
        float* __restrict__ out) {
    __shared__ unsigned short ThT[HALO_J * PITCH_T];   // [hc][hr], bf16, ~30.8KB

    const int tid = threadIdx.x;
    const int j0 = blockIdx.x * TJ;
    const int i0 = blockIdx.y * TI;
    const int b0 = blockIdx.z;

    const float bpar = pp[441];
    const float rc2  = pp[442];
    const float sub0 = pp[443];
    const float sub1 = pp[444];
    const float x0   = pp[445];
    const float y0   = pp[446];
    const float SSTEP = 2.0f / 1023.0f;

    const float* sb = src + (size_t)b0 * (HH * (size_t)WW);

    // ---- fill transposed halo tile: 4 adjacent hr per thread per iter ----
    // 16 independent global loads in flight per iteration; per-row math hoisted.
    for (int p = tid; p < (HALO_J * FILL_I) / 4; p += 256) {
        int hc  = p / (FILL_I / 4);
        int hr0 = (p - hc * (FILL_I / 4)) << 2;
        unsigned int pk0 = 0, pk1 = 0;
        if (hr0 < VALID_I) {
            int J = j0 - 10 + hc;        // y index
            if ((unsigned)J < HH) {
                float yv = fmaf((float)J, SSTEP, -1.0f);
                float dy = yv - y0;
                float dyterm = dy * dy + rc2;
                float vals[4];
#pragma unroll
                for (int e = 0; e < 4; ++e) {
                    int I = i0 - 10 + hr0 + e;   // x index
                    float val = 0.f;
                    if ((unsigned)I < WW) {
                        float xv = fmaf((float)I, SSTEP, -1.0f);
                        float dx = xv - x0;
                        float s = bpar * __builtin_amdgcn_rsqf(dx * dx + dyterm);
                        float gx = xv - dx * s + sub0;
                        float gy = yv - dy * s + sub1;
                        float ix = (gx + 1.0f) * (0.5f * 1023.0f);
                        float iy = (gy + 1.0f) * (0.5f * 1023.0f);
                        float fx = floorf(ix), fy = floorf(iy);
                        float wx1 = ix - fx, wy1 = iy - fy;
                        float wx0 = 1.f - wx1, wy0 = 1.f - wy1;
                        int xi0 = (int)fx, yi0 = (int)fy;
                        int xi1 = xi0 + 1, yi1 = yi0 + 1;
                        int xc0 = min(max(xi0, 0), WW - 1);
                        int xc1 = min(max(xi1, 0), WW - 1);
                        int yc0 = min(max(yi0, 0), HH - 1);
                        int yc1 = min(max(yi1, 0), HH - 1);
                        bool vx0 = (unsigned)xi0 < WW, vx1 = (unsigned)xi1 < WW;
                        bool vy0 = (unsigned)yi0 < HH, vy1 = (unsigned)yi1 < HH;
                        float w00 = (vx0 && vy0) ? wy0 * wx0 : 0.f;
                        float w01 = (vx1 && vy0) ? wy0 * wx1 : 0.f;
                        float w10 = (vx0 && vy1) ? wy1 * wx0 : 0.f;
                        float w11 = (vx1 && vy1) ? wy1 * wx1 : 0.f;
                        float v00 = sb[yc0 * WW + xc0];
                        float v01 = sb[yc0 * WW + xc1];
                        float v10 = sb[yc1 * WW + xc0];
                        float v11 = sb[yc1 * WW + xc1];
                        val = v00 * w00 + v01 * w01 + v10 * w10 + v11 * w11;
                    }
                    vals[e] = val;
                }
                pk0 = (unsigned int)f2bf(vals[0]) | ((unsigned int)f2bf(vals[1]) << 16);
                pk1 = (unsigned int)f2bf(vals[2]) | ((unsigned int)f2bf(vals[3]) << 16);
            }
        }
        // hr0 multiple of 4, row pitch 208B -> 8B aligned packed store
        uint2 pk; pk.x = pk0; pk.y = pk1;
        *(uint2*)&ThT[hc * PITCH_T + hr0] = pk;
    }
    __syncthreads();

    // ---- MFMA conv: wave wv owns j in [32*wv, 32*wv+32), 2 M-blocks (TI=64) ----
    const int lane = tid & 63;
    const int wv = tid >> 6;
    const int nrow = lane & 31;          // n (j) for B and C; m (i) for A
    const int khalf = lane >> 5;

    float16 acc[2];
#pragma unroll
    for (int m = 0; m < 2; ++m)
#pragma unroll
        for (int q = 0; q < 16; ++q) acc[m][q] = 0.f;

    const short8* Aall = (const short8*)(pp + AOFF);

#pragma unroll 1
    for (int v = 0; v < 21; ++v) {
        short8 Af[4];
#pragma unroll
        for (int d = 0; d < 4; ++d)
            Af[d] = Aall[(v * 4 + d) * 64 + lane];     // L2-resident, shared by all blocks

        const unsigned short* bp = &ThT[(32 * wv + nrow + v) * PITCH_T + khalf * 8];
        short8 Bf[6];
#pragma unroll
        for (int c = 0; c < 6; ++c)
            Bf[c] = *(const short8*)&bp[16 * c];

#pragma unroll
        for (int mq = 0; mq < 2; ++mq) {
#pragma unroll
            for (int d = 0; d < 4; ++d)
                acc[mq] = __builtin_amdgcn_mfma_f32_32x32x16_bf16(
                    Af[d], Bf[2 * mq + d], acc[mq], 0, 0, 0);
        }
    }

    // ---- epilogue: C/D layout col=lane&31, row=(reg&3)+8*(reg>>2)+4*(lane>>5) ----
    float* ob = out + (size_t)b0 * (WW * (size_t)HH);
    const int gj = j0 + 32 * wv + nrow;
#pragma unroll
    for (int mq = 0; mq < 2; ++mq) {
#pragma unroll
        for (int reg = 0; reg < 16; ++reg) {
            int row = (reg & 3) + 8 * (reg >> 2) + 4 * khalf;
            int gi = i0 + 32 * mq + row;
            ob[(size_t)gi * HH + gj] = acc[mq][reg];
        }
    }
}

extern "C" void kernel_launch(void* const* d_in, const int* in_sizes, int n_in,
                              void* d_out, int out_size, void* d_ws, size_t ws_size,
                              hipStream_t stream) {
    const float* src     = (const float*)d_in[0];
    const float* raw_psf = (const float*)d_in[1];
    const float* x0      = (const float*)d_in[2];
    const float* y0      = (const float*)d_in[3];
    const float* raw_b   = (const float*)d_in[4];
    const float* raw_rc  = (const float*)d_in[5];
    const float* raw_sub = (const float*)d_in[6];
    float* ws = (float*)d_ws;

    prep_kernel<<<1, 512, 0, stream>>>(raw_psf, x0, y0, raw_b, raw_rc, raw_sub, ws);

    dim3 grid(HH / TJ, WW / TI, 16);   // (8, 16, 16) = 2048 blocks
    fused_kernel<<<grid, 256, 0, stream>>>(src, ws, (float*)d_out);
}

// Round 4
// 240.370 us; speedup vs baseline: 1.1007x; 1.0778x over previous
//
#include <hip/hip_runtime.h>
#include <math.h>

#define WW 1024
#define HH 1024
#define TI 64          // output tile extent in i (x)
#define TJ 128         // output tile extent in j (y)
#define HALO_J 148     // hc (y) extent = TJ + 20
#define VALID_I 84     // valid hr (x) extent = TI + 20
#define FILL_I 96      // filled hr extent (chunks read up to x=96; [84,96) zero)
#define PITCH_T 104    // ThT row pitch in elems; 208B row, 52 dwords == 20 mod 32
#define AOFF 448       // float offset of A-pattern table in ws

typedef short short8 __attribute__((ext_vector_type(8)));
typedef float float16 __attribute__((ext_vector_type(16)));

__device__ __forceinline__ unsigned short f2bf(float f) {
    union { float f; unsigned int u; } c; c.f = f;
    unsigned int u = c.u;
    return (unsigned short)((u + 0x7FFFu + ((u >> 16) & 1u)) >> 16);
}

// ---------------- prep: PSF normalize, params, Toeplitz A-pattern table ------
// A-pattern: for chunk-offset d in [0,4), lane l (m=l&31, k0=8*(l>>5)),
//   Apat[v][d][l][q] = P_bf16[16d + k0 + q - m][v]   (0 if u outside [0,20])
// Note: independent of the mq output-block (chunk index 2*mq+d shifts B, not A).
__global__ void prep_kernel(const float* __restrict__ raw_psf,
                            const float* __restrict__ x0p, const float* __restrict__ y0p,
                            const float* __restrict__ raw_b, const float* __restrict__ raw_rc,
                            const float* __restrict__ raw_sub,
                            float* __restrict__ ws) {
    __shared__ float red[512];
    __shared__ float psn[441];
    int t = threadIdx.x;
    float v = 0.f;
    if (t < 441) v = fmaxf(raw_psf[t], 0.f);
    red[t] = v;
    __syncthreads();
    for (int s = 256; s > 0; s >>= 1) {
        if (t < s) red[t] += red[t + s];
        __syncthreads();
    }
    float sum = fmaxf(red[0], 1e-12f);
    if (t < 441) { float pn = v / sum; ws[t] = pn; psn[t] = pn; }
    if (t == 0) {
        float b  = log1pf(expf(raw_b[0]))  + 1e-8f;
        float rc = log1pf(expf(raw_rc[0])) + 1e-8f;
        ws[441] = b;
        ws[442] = 1e-12f + rc * rc;
        ws[443] = 0.25f * tanhf(raw_sub[0]);
        ws[444] = 0.25f * tanhf(raw_sub[1]);
        ws[445] = x0p[0];
        ws[446] = y0p[0];
    }
    __syncthreads();

    short* A = (short*)(ws + AOFF);
    for (int g = t; g < 21 * 256; g += 512) {      // g = v*256 + d*64 + l
        int vv = g >> 8;
        int r  = g & 255;
        int d  = r >> 6;
        int l  = r & 63;
        int m  = l & 31;
        int k0 = (l >> 5) << 3;
        short8 o8;
#pragma unroll
        for (int q = 0; q < 8; ++q) {
            int u = 16 * d + k0 + q - m;
            unsigned short pv = 0;
            if ((unsigned)u <= 20u) pv = f2bf(psn[u * 21 + vv]);
            o8[q] = (short)pv;
        }
        *(short8*)&A[(size_t)g * 8] = o8;
    }
}

// ---------------- fused: bilinear warp -> bf16 LDS (transposed) -> MFMA conv -
__global__ __launch_bounds__(256, 4) void fused_kernel(
        const float* __restrict__ src, const float* __restrict__ pp,
        float* __restrict__ out) {
    __shared__ unsigned short ThT[HALO_J * PITCH_T];   // [hc][hr], bf16, ~30.8KB

    const int tid = threadIdx.x;
    const int j0 = blockIdx.x * TJ;
    const int i0 = blockIdx.y * TI;
    const int b0 = blockIdx.z;

    const float bpar = pp[441];
    const float rc2  = pp[442];
    const float sub0 = pp[443];
    const float sub1 = pp[444];
    const float x0   = pp[445];
    const float y0   = pp[446];
    const float SSTEP = 2.0f / 1023.0f;

    const float* sb = src + (size_t)b0 * (HH * (size_t)WW);

    // ---- fill transposed halo tile: wave-contiguous hr for coalesced gather ----
    // n = hc*FILL_I + hr linearized; thread handles {n, n+256, n+512, n+768} per
    // 1024-chunk so each e-step has 64 CONSECUTIVE hr across a wave's lanes
    // (source stride ~1px -> ~5-8 cache lines per wave-load vs ~17 before).
    // 16 independent global loads in flight per chunk.
    const int NELEM = HALO_J * FILL_I;    // 14208
#pragma unroll 1
    for (int base = 0; base < NELEM; base += 1024) {
        float vals[4];
        int offs[4];
#pragma unroll
        for (int e = 0; e < 4; ++e) {
            int n = base + (e << 8) + tid;
            float val = 0.f;
            int off = -1;
            if (n < NELEM) {
                int hc = (int)((unsigned)n / 96u);
                int hr = n - hc * 96;
                off = hc * PITCH_T + hr;
                int J = j0 - 10 + hc;        // y index
                int I = i0 - 10 + hr;        // x index
                if (hr < VALID_I && (unsigned)J < HH && (unsigned)I < WW) {
                    float yv = fmaf((float)J, SSTEP, -1.0f);
                    float xv = fmaf((float)I, SSTEP, -1.0f);
                    float dx = xv - x0;
                    float dy = yv - y0;
                    float s = bpar * __builtin_amdgcn_rsqf(dx * dx + dy * dy + rc2);
                    float gx = xv - dx * s + sub0;
                    float gy = yv - dy * s + sub1;
                    float ix = (gx + 1.0f) * (0.5f * 1023.0f);
                    float iy = (gy + 1.0f) * (0.5f * 1023.0f);
                    float fx = floorf(ix), fy = floorf(iy);
                    float wx1 = ix - fx, wy1 = iy - fy;
                    float wx0 = 1.f - wx1, wy0 = 1.f - wy1;
                    int xi0 = (int)fx, yi0 = (int)fy;
                    int xi1 = xi0 + 1, yi1 = yi0 + 1;
                    int xc0 = min(max(xi0, 0), WW - 1);
                    int xc1 = min(max(xi1, 0), WW - 1);
                    int yc0 = min(max(yi0, 0), HH - 1);
                    int yc1 = min(max(yi1, 0), HH - 1);
                    bool vx0 = (unsigned)xi0 < WW, vx1 = (unsigned)xi1 < WW;
                    bool vy0 = (unsigned)yi0 < HH, vy1 = (unsigned)yi1 < HH;
                    float w00 = (vx0 && vy0) ? wy0 * wx0 : 0.f;
                    float w01 = (vx1 && vy0) ? wy0 * wx1 : 0.f;
                    float w10 = (vx0 && vy1) ? wy1 * wx0 : 0.f;
                    float w11 = (vx1 && vy1) ? wy1 * wx1 : 0.f;
                    float v00 = sb[yc0 * WW + xc0];
                    float v01 = sb[yc0 * WW + xc1];
                    float v10 = sb[yc1 * WW + xc0];
                    float v11 = sb[yc1 * WW + xc1];
                    val = v00 * w00 + v01 * w01 + v10 * w10 + v11 * w11;
                }
            }
            vals[e] = val;
            offs[e] = off;
        }
#pragma unroll
        for (int e = 0; e < 4; ++e) {
            if (offs[e] >= 0) ThT[offs[e]] = f2bf(vals[e]);
        }
    }
    __syncthreads();

    // ---- MFMA conv: wave wv owns j in [32*wv, 32*wv+32), 2 M-blocks (TI=64) ----
    const int lane = tid & 63;
    const int wv = tid >> 6;
    const int nrow = lane & 31;          // n (j) for B and C; m (i) for A
    const int khalf = lane >> 5;

    float16 acc[2];
#pragma unroll
    for (int m = 0; m < 2; ++m)
#pragma unroll
        for (int q = 0; q < 16; ++q) acc[m][q] = 0.f;

    const short8* Aall = (const short8*)(pp + AOFF);

#pragma unroll 1
    for (int v = 0; v < 21; ++v) {
        short8 Af[4];
#pragma unroll
        for (int d = 0; d < 4; ++d)
            Af[d] = Aall[(v * 4 + d) * 64 + lane];     // L2-resident, shared by all blocks

        const unsigned short* bp = &ThT[(32 * wv + nrow + v) * PITCH_T + khalf * 8];
        short8 Bf[6];
#pragma unroll
        for (int c = 0; c < 6; ++c)
            Bf[c] = *(const short8*)&bp[16 * c];

#pragma unroll
        for (int mq = 0; mq < 2; ++mq) {
#pragma unroll
            for (int d = 0; d < 4; ++d)
                acc[mq] = __builtin_amdgcn_mfma_f32_32x32x16_bf16(
                    Af[d], Bf[2 * mq + d], acc[mq], 0, 0, 0);
        }
    }

    // ---- epilogue: C/D layout col=lane&31, row=(reg&3)+8*(reg>>2)+4*(lane>>5) ----
    float* ob = out + (size_t)b0 * (WW * (size_t)HH);
    const int gj = j0 + 32 * wv + nrow;
#pragma unroll
    for (int mq = 0; mq < 2; ++mq) {
#pragma unroll
        for (int reg = 0; reg < 16; ++reg) {
            int row = (reg & 3) + 8 * (reg >> 2) + 4 * khalf;
            int gi = i0 + 32 * mq + row;
            ob[(size_t)gi * HH + gj] = acc[mq][reg];
        }
    }
}

extern "C" void kernel_launch(void* const* d_in, const int* in_sizes, int n_in,
                              void* d_out, int out_size, void* d_ws, size_t ws_size,
                              hipStream_t stream) {
    const float* src     = (const float*)d_in[0];
    const float* raw_psf = (const float*)d_in[1];
    const float* x0      = (const float*)d_in[2];
    const float* y0      = (const float*)d_in[3];
    const float* raw_b   = (const float*)d_in[4];
    const float* raw_rc  = (const float*)d_in[5];
    const float* raw_sub = (const float*)d_in[6];
    float* ws = (float*)d_ws;

    prep_kernel<<<1, 512, 0, stream>>>(raw_psf, x0, y0, raw_b, raw_rc, raw_sub, ws);

    dim3 grid(HH / TJ, WW / TI, 16);   // (8, 16, 16) = 2048 blocks
    fused_kernel<<<grid, 256, 0, stream>>>(src, ws, (float*)d_out);
}

// Round 5
// 216.899 us; speedup vs baseline: 1.2199x; 1.1082x over previous
//
#include <hip/hip_runtime.h>
#include <math.h>

#define WW 1024
#define HH 1024
#define TI 64          // output tile extent in i (x)
#define TJ 128         // output tile extent in j (y)
#define HALO_J 148     // hc (y) extent = TJ + 20
#define VALID_I 84     // valid hr extent for fallback fused kernel
#define FILL_I 96      // fallback fill extent
#define PITCH_T 104    // ThT row pitch in elems; 208B, 52 dwords == 20 mod 32 (conflict-free)
#define AOFF 448       // float offset of A-pattern table (origin i0-10, fallback)
#define AOFF2 21952    // float offset of shifted A-pattern table (origin i0-16, split path)
#define YOFF 43520     // float offset of bf16 warped image (32MB)
#define NEED_WS (174080u + 33554432u)

typedef short short8 __attribute__((ext_vector_type(8)));
typedef float float16 __attribute__((ext_vector_type(16)));

__device__ __forceinline__ unsigned short f2bf(float f) {
    union { float f; unsigned int u; } c; c.f = f;
    unsigned int u = c.u;
    return (unsigned short)((u + 0x7FFFu + ((u >> 16) & 1u)) >> 16);
}

// warped-image sample at integer grid (I, J); val=0 outside image (conv zero-pad)
__device__ __forceinline__ float warp_sample(const float* __restrict__ sb, int I, int J,
                                             float bpar, float rc2, float sub0, float sub1,
                                             float x0, float y0) {
    const float SSTEP = 2.0f / 1023.0f;
    float yv = fmaf((float)J, SSTEP, -1.0f);
    float xv = fmaf((float)I, SSTEP, -1.0f);
    float dx = xv - x0;
    float dy = yv - y0;
    float s = bpar * __builtin_amdgcn_rsqf(dx * dx + dy * dy + rc2);
    float gx = xv - dx * s + sub0;
    float gy = yv - dy * s + sub1;
    float ix = (gx + 1.0f) * (0.5f * 1023.0f);
    float iy = (gy + 1.0f) * (0.5f * 1023.0f);
    float fx = floorf(ix), fy = floorf(iy);
    float wx1 = ix - fx, wy1 = iy - fy;
    float wx0 = 1.f - wx1, wy0 = 1.f - wy1;
    int xi0 = (int)fx, yi0 = (int)fy;
    int xi1 = xi0 + 1, yi1 = yi0 + 1;
    int xc0 = min(max(xi0, 0), WW - 1);
    int xc1 = min(max(xi1, 0), WW - 1);
    int yc0 = min(max(yi0, 0), HH - 1);
    int yc1 = min(max(yi1, 0), HH - 1);
    bool vx0 = (unsigned)xi0 < WW, vx1 = (unsigned)xi1 < WW;
    bool vy0 = (unsigned)yi0 < HH, vy1 = (unsigned)yi1 < HH;
    float w00 = (vx0 && vy0) ? wy0 * wx0 : 0.f;
    float w01 = (vx1 && vy0) ? wy0 * wx1 : 0.f;
    float w10 = (vx0 && vy1) ? wy1 * wx0 : 0.f;
    float w11 = (vx1 && vy1) ? wy1 * wx1 : 0.f;
    float v00 = sb[yc0 * WW + xc0];
    float v01 = sb[yc0 * WW + xc1];
    float v10 = sb[yc1 * WW + xc0];
    float v11 = sb[yc1 * WW + xc1];
    return v00 * w00 + v01 * w01 + v10 * w10 + v11 * w11;
}

// ---------------- prep: PSF normalize, params, both Toeplitz A-pattern tables
// Table1 (AOFF,  fallback): u = 16d + k0 + q - m      (B x-origin i0-10)
// Table2 (AOFF2, split):    u = 16d + k0 + q - m - 6  (B x-origin i0-16)
__global__ void prep_kernel(const float* __restrict__ raw_psf,
                            const float* __restrict__ x0p, const float* __restrict__ y0p,
                            const float* __restrict__ raw_b, const float* __restrict__ raw_rc,
                            const float* __restrict__ raw_sub,
                            float* __restrict__ ws) {
    __shared__ float red[512];
    __shared__ float psn[441];
    int t = threadIdx.x;
    float v = 0.f;
    if (t < 441) v = fmaxf(raw_psf[t], 0.f);
    red[t] = v;
    __syncthreads();
    for (int s = 256; s > 0; s >>= 1) {
        if (t < s) red[t] += red[t + s];
        __syncthreads();
    }
    float sum = fmaxf(red[0], 1e-12f);
    if (t < 441) { float pn = v / sum; ws[t] = pn; psn[t] = pn; }
    if (t == 0) {
        float b  = log1pf(expf(raw_b[0]))  + 1e-8f;
        float rc = log1pf(expf(raw_rc[0])) + 1e-8f;
        ws[441] = b;
        ws[442] = 1e-12f + rc * rc;
        ws[443] = 0.25f * tanhf(raw_sub[0]);
        ws[444] = 0.25f * tanhf(raw_sub[1]);
        ws[445] = x0p[0];
        ws[446] = y0p[0];
    }
    __syncthreads();

    short* A  = (short*)(ws + AOFF);
    short* A2 = (short*)(ws + AOFF2);
    for (int g = t; g < 21 * 256; g += 512) {      // g = v*256 + d*64 + l
        int vv = g >> 8;
        int r  = g & 255;
        int d  = r >> 6;
        int l  = r & 63;
        int m  = l & 31;
        int k0 = (l >> 5) << 3;
        short8 o8, o8b;
#pragma unroll
        for (int q = 0; q < 8; ++q) {
            int u = 16 * d + k0 + q - m;
            unsigned short pv = 0, pv2 = 0;
            if ((unsigned)u <= 20u) pv = f2bf(psn[u * 21 + vv]);
            int u2 = u - 6;
            if ((unsigned)u2 <= 20u) pv2 = f2bf(psn[u2 * 21 + vv]);
            o8[q]  = (short)pv;
            o8b[q] = (short)pv2;
        }
        *(short8*)&A[(size_t)g * 8]  = o8;
        *(short8*)&A2[(size_t)g * 8] = o8b;
    }
}

// ---------------- split kernel 1: warp each pixel EXACTLY ONCE -> bf16 image --
// n = b0*2^20 + J*1024 + I; lanes contiguous in I (coalesced gather+store).
__global__ __launch_bounds__(256, 4) void warp_kernel(
        const float* __restrict__ src, const float* __restrict__ pp,
        unsigned short* __restrict__ yw) {
    const float bpar = pp[441], rc2 = pp[442];
    const float sub0 = pp[443], sub1 = pp[444];
    const float x0 = pp[445], y0 = pp[446];
    const int base = blockIdx.x * 8192;
    const int tid = threadIdx.x;
#pragma unroll 4
    for (int it = 0; it < 32; ++it) {
        int n = base + it * 256 + tid;
        int b0 = n >> 20;
        int J = (n >> 10) & 1023;
        int I = n & 1023;
        const float* sb = src + ((size_t)b0 << 20);
        float val = warp_sample(sb, I, J, bpar, rc2, sub0, sub1, x0, y0);
        yw[n] = f2bf(val);
    }
}

// ---------------- split kernel 2: stage bf16 tile (no warp math) -> MFMA conv -
// Tile x-origin i0-16 (16B-aligned rows); A-table2 absorbs the -6 shift.
// 12 chunks/row of 16B; every boundary chunk is fully in- or out-of-bounds.
__global__ __launch_bounds__(256, 4) void conv_kernel(
        const unsigned short* __restrict__ yw, const float* __restrict__ pp,
        float* __restrict__ out) {
    __shared__ unsigned short ThT[HALO_J * PITCH_T];   // [hc][hr'], 30.8KB

    const int tid = threadIdx.x;
    const int j0 = blockIdx.x * TJ;
    const int i0 = blockIdx.y * TI;
    const int b0 = blockIdx.z;

    const unsigned short* wb = yw + ((size_t)b0 << 20);

    // ---- staging: 148 rows x 12 chunks = 1776 16B loads, zero-fill OOB ----
    for (int p = tid; p < HALO_J * 12; p += 256) {
        int hc = (int)((unsigned)p / 12u);
        int c  = p - hc * 12;
        int J  = j0 - 10 + hc;
        int xs = i0 - 16 + c * 8;
        short8 d8 = {0, 0, 0, 0, 0, 0, 0, 0};
        if ((unsigned)J < HH && (unsigned)xs < WW)
            d8 = *(const short8*)&wb[J * WW + xs];
        *(short8*)&ThT[hc * PITCH_T + c * 8] = d8;
    }
    __syncthreads();

    // ---- MFMA conv (identical structure; A from shifted table) ----
    const int lane = tid & 63;
    const int wv = tid >> 6;
    const int nrow = lane & 31;
    const int khalf = lane >> 5;

    float16 acc[2];
#pragma unroll
    for (int m = 0; m < 2; ++m)
#pragma unroll
        for (int q = 0; q < 16; ++q) acc[m][q] = 0.f;

    const short8* Aall = (const short8*)(pp + AOFF2);

#pragma unroll 1
    for (int v = 0; v < 21; ++v) {
        short8 Af[4];
#pragma unroll
        for (int d = 0; d < 4; ++d)
            Af[d] = Aall[(v * 4 + d) * 64 + lane];     // L2-resident

        const unsigned short* bp = &ThT[(32 * wv + nrow + v) * PITCH_T + khalf * 8];
        short8 Bf[6];
#pragma unroll
        for (int c = 0; c < 6; ++c)
            Bf[c] = *(const short8*)&bp[16 * c];

#pragma unroll
        for (int mq = 0; mq < 2; ++mq) {
#pragma unroll
            for (int d = 0; d < 4; ++d)
                acc[mq] = __builtin_amdgcn_mfma_f32_32x32x16_bf16(
                    Af[d], Bf[2 * mq + d], acc[mq], 0, 0, 0);
        }
    }

    float* ob = out + (size_t)b0 * (WW * (size_t)HH);
    const int gj = j0 + 32 * wv + nrow;
#pragma unroll
    for (int mq = 0; mq < 2; ++mq) {
#pragma unroll
        for (int reg = 0; reg < 16; ++reg) {
            int row = (reg & 3) + 8 * (reg >> 2) + 4 * khalf;
            int gi = i0 + 32 * mq + row;
            ob[(size_t)gi * HH + gj] = acc[mq][reg];
        }
    }
}

// ---------------- fallback: round-4 fused kernel (used if ws too small) ------
__global__ __launch_bounds__(256, 4) void fused_kernel(
        const float* __restrict__ src, const float* __restrict__ pp,
        float* __restrict__ out) {
    __shared__ unsigned short ThT[HALO_J * PITCH_T];

    const int tid = threadIdx.x;
    const int j0 = blockIdx.x * TJ;
    const int i0 = blockIdx.y * TI;
    const int b0 = blockIdx.z;

    const float bpar = pp[441], rc2 = pp[442];
    const float sub0 = pp[443], sub1 = pp[444];
    const float x0 = pp[445], y0 = pp[446];

    const float* sb = src + (size_t)b0 * (HH * (size_t)WW);

    const int NELEM = HALO_J * FILL_I;
#pragma unroll 1
    for (int base = 0; base < NELEM; base += 1024) {
        float vals[4];
        int offs[4];
#pragma unroll
        for (int e = 0; e < 4; ++e) {
            int n = base + (e << 8) + tid;
            float val = 0.f;
            int off = -1;
            if (n < NELEM) {
                int hc = (int)((unsigned)n / 96u);
                int hr = n - hc * 96;
                off = hc * PITCH_T + hr;
                int J = j0 - 10 + hc;
                int I = i0 - 10 + hr;
                if (hr < VALID_I && (unsigned)J < HH && (unsigned)I < WW)
                    val = warp_sample(sb, I, J, bpar, rc2, sub0, sub1, x0, y0);
            }
            vals[e] = val;
            offs[e] = off;
        }
#pragma unroll
        for (int e = 0; e < 4; ++e) {
            if (offs[e] >= 0) ThT[offs[e]] = f2bf(vals[e]);
        }
    }
    __syncthreads();

    const int lane = tid & 63;
    const int wv = tid >> 6;
    const int nrow = lane & 31;
    const int khalf = lane >> 5;

    float16 acc[2];
#pragma unroll
    for (int m = 0; m < 2; ++m)
#pragma unroll
        for (int q = 0; q < 16; ++q) acc[m][q] = 0.f;

    const short8* Aall = (const short8*)(pp + AOFF);

#pragma unroll 1
    for (int v = 0; v < 21; ++v) {
        short8 Af[4];
#pragma unroll
        for (int d = 0; d < 4; ++d)
            Af[d] = Aall[(v * 4 + d) * 64 + lane];

        const unsigned short* bp = &ThT[(32 * wv + nrow + v) * PITCH_T + khalf * 8];
        short8 Bf[6];
#pragma unroll
        for (int c = 0; c < 6; ++c)
            Bf[c] = *(const short8*)&bp[16 * c];

#pragma unroll
        for (int mq = 0; mq < 2; ++mq) {
#pragma unroll
            for (int d = 0; d < 4; ++d)
                acc[mq] = __builtin_amdgcn_mfma_f32_32x32x16_bf16(
                    Af[d], Bf[2 * mq + d], acc[mq], 0, 0, 0);
        }
    }

    float* ob = out + (size_t)b0 * (WW * (size_t)HH);
    const int gj = j0 + 32 * wv + nrow;
#pragma unroll
    for (int mq = 0; mq < 2; ++mq) {
#pragma unroll
        for (int reg = 0; reg < 16; ++reg) {
            int row = (reg & 3) + 8 * (reg >> 2) + 4 * khalf;
            int gi = i0 + 32 * mq + row;
            ob[(size_t)gi * HH + gj] = acc[mq][reg];
        }
    }
}

extern "C" void kernel_launch(void* const* d_in, const int* in_sizes, int n_in,
                              void* d_out, int out_size, void* d_ws, size_t ws_size,
                              hipStream_t stream) {
    const float* src     = (const float*)d_in[0];
    const float* raw_psf = (const float*)d_in[1];
    const float* x0      = (const float*)d_in[2];
    const float* y0      = (const float*)d_in[3];
    const float* raw_b   = (const float*)d_in[4];
    const float* raw_rc  = (const float*)d_in[5];
    const float* raw_sub = (const float*)d_in[6];
    float* ws = (float*)d_ws;

    prep_kernel<<<1, 512, 0, stream>>>(raw_psf, x0, y0, raw_b, raw_rc, raw_sub, ws);

    dim3 grid(HH / TJ, WW / TI, 16);   // (8, 16, 16) = 2048 blocks
    if (ws_size >= (size_t)NEED_WS) {
        unsigned short* yw = (unsigned short*)(ws + YOFF);
        warp_kernel<<<2048, 256, 0, stream>>>(src, ws, yw);
        conv_kernel<<<grid, 256, 0, stream>>>(yw, ws, (float*)d_out);
    } else {
        fused_kernel<<<grid, 256, 0, stream>>>(src, ws, (float*)d_out);
    }
}

// Round 6
// 210.382 us; speedup vs baseline: 1.2576x; 1.0310x over previous
//
#include <hip/hip_runtime.h>
#include <math.h>

#define WW 1024
#define HH 1024
#define TI 64          // output tile extent in i (x)
#define TJ 128         // output tile extent in j (y)
#define HALO_J 148     // hc (y) extent = TJ + 20
#define VALID_I 84     // valid hr extent for fallback fused kernel
#define FILL_I 96      // fallback fill extent
#define PITCH_T 104    // ThT row pitch in elems; 208B, 52 dwords == 20 mod 32 (conflict-free)
#define AOFF 448       // float offset of A-pattern table (origin i0-10, fallback)
#define AOFF2 21952    // float offset of shifted A-pattern table (origin i0-16, split path)
#define YOFF 43520     // float offset of bf16 warped image (32MB)
#define NEED_WS (174080u + 33554432u)

typedef short short8 __attribute__((ext_vector_type(8)));
typedef float float16 __attribute__((ext_vector_type(16)));

__device__ __forceinline__ unsigned short f2bf(float f) {
    union { float f; unsigned int u; } c; c.f = f;
    unsigned int u = c.u;
    return (unsigned short)((u + 0x7FFFu + ((u >> 16) & 1u)) >> 16);
}

// warped-image sample at integer grid (I, J); val=0 outside image (conv zero-pad)
__device__ __forceinline__ float warp_sample(const float* __restrict__ sb, int I, int J,
                                             float bpar, float rc2, float sub0, float sub1,
                                             float x0, float y0) {
    const float SSTEP = 2.0f / 1023.0f;
    float yv = fmaf((float)J, SSTEP, -1.0f);
    float xv = fmaf((float)I, SSTEP, -1.0f);
    float dx = xv - x0;
    float dy = yv - y0;
    float s = bpar * __builtin_amdgcn_rsqf(dx * dx + dy * dy + rc2);
    float gx = xv - dx * s + sub0;
    float gy = yv - dy * s + sub1;
    float ix = (gx + 1.0f) * (0.5f * 1023.0f);
    float iy = (gy + 1.0f) * (0.5f * 1023.0f);
    float fx = floorf(ix), fy = floorf(iy);
    float wx1 = ix - fx, wy1 = iy - fy;
    float wx0 = 1.f - wx1, wy0 = 1.f - wy1;
    int xi0 = (int)fx, yi0 = (int)fy;
    int xi1 = xi0 + 1, yi1 = yi0 + 1;
    int xc0 = min(max(xi0, 0), WW - 1);
    int xc1 = min(max(xi1, 0), WW - 1);
    int yc0 = min(max(yi0, 0), HH - 1);
    int yc1 = min(max(yi1, 0), HH - 1);
    bool vx0 = (unsigned)xi0 < WW, vx1 = (unsigned)xi1 < WW;
    bool vy0 = (unsigned)yi0 < HH, vy1 = (unsigned)yi1 < HH;
    float w00 = (vx0 && vy0) ? wy0 * wx0 : 0.f;
    float w01 = (vx1 && vy0) ? wy0 * wx1 : 0.f;
    float w10 = (vx0 && vy1) ? wy1 * wx0 : 0.f;
    float w11 = (vx1 && vy1) ? wy1 * wx1 : 0.f;
    float v00 = sb[yc0 * WW + xc0];
    float v01 = sb[yc0 * WW + xc1];
    float v10 = sb[yc1 * WW + xc0];
    float v11 = sb[yc1 * WW + xc1];
    return v00 * w00 + v01 * w01 + v10 * w10 + v11 * w11;
}

// ---------------- prep: PSF normalize, params, both Toeplitz A-pattern tables
__global__ void prep_kernel(const float* __restrict__ raw_psf,
                            const float* __restrict__ x0p, const float* __restrict__ y0p,
                            const float* __restrict__ raw_b, const float* __restrict__ raw_rc,
                            const float* __restrict__ raw_sub,
                            float* __restrict__ ws) {
    __shared__ float red[512];
    __shared__ float psn[441];
    int t = threadIdx.x;
    float v = 0.f;
    if (t < 441) v = fmaxf(raw_psf[t], 0.f);
    red[t] = v;
    __syncthreads();
    for (int s = 256; s > 0; s >>= 1) {
        if (t < s) red[t] += red[t + s];
        __syncthreads();
    }
    float sum = fmaxf(red[0], 1e-12f);
    if (t < 441) { float pn = v / sum; ws[t] = pn; psn[t] = pn; }
    if (t == 0) {
        float b  = log1pf(expf(raw_b[0]))  + 1e-8f;
        float rc = log1pf(expf(raw_rc[0])) + 1e-8f;
        ws[441] = b;
        ws[442] = 1e-12f + rc * rc;
        ws[443] = 0.25f * tanhf(raw_sub[0]);
        ws[444] = 0.25f * tanhf(raw_sub[1]);
        ws[445] = x0p[0];
        ws[446] = y0p[0];
    }
    __syncthreads();

    short* A  = (short*)(ws + AOFF);
    short* A2 = (short*)(ws + AOFF2);
    for (int g = t; g < 21 * 256; g += 512) {      // g = v*256 + d*64 + l
        int vv = g >> 8;
        int r  = g & 255;
        int d  = r >> 6;
        int l  = r & 63;
        int m  = l & 31;
        int k0 = (l >> 5) << 3;
        short8 o8, o8b;
#pragma unroll
        for (int q = 0; q < 8; ++q) {
            int u = 16 * d + k0 + q - m;
            unsigned short pv = 0, pv2 = 0;
            if ((unsigned)u <= 20u) pv = f2bf(psn[u * 21 + vv]);
            int u2 = u - 6;
            if ((unsigned)u2 <= 20u) pv2 = f2bf(psn[u2 * 21 + vv]);
            o8[q]  = (short)pv;
            o8b[q] = (short)pv2;
        }
        *(short8*)&A[(size_t)g * 8]  = o8;
        *(short8*)&A2[(size_t)g * 8] = o8b;
    }
}

// ---------------- split kernel 1: warp each pixel EXACTLY ONCE -> bf16 image --
// Block covers 8 consecutive rows of one image. Per row: hoist row-invariant
// math; process 4-pixel quads with a WAVE-UNIFORM fast/slow branch so the fast
// block is straight-line (16 independent loads in flight, no clamps/selects).
__global__ __launch_bounds__(256, 4) void warp_kernel(
        const float* __restrict__ src, const float* __restrict__ pp,
        unsigned short* __restrict__ yw) {
    const float bpar = pp[441], rc2 = pp[442];
    const float sub0 = pp[443], sub1 = pp[444];
    const float x0 = pp[445], y0 = pp[446];
    const float SSTEP = 2.0f / 1023.0f;

    const int tid = threadIdx.x;
    const int nb  = blockIdx.x;            // 2048 blocks = 16 images x 128
    const int b0  = nb >> 7;
    const int J0  = (nb & 127) << 3;       // 8 rows per block
    const float* sb = src + ((size_t)b0 << 20);
    unsigned short* yb = yw + ((size_t)b0 << 20) + ((size_t)J0 << 10);

#pragma unroll 1
    for (int jr = 0; jr < 8; ++jr) {
        int J = J0 + jr;
        float yv = fmaf((float)J, SSTEP, -1.0f);
        float dy = yv - y0;
        float dyt = fmaf(dy, dy, rc2);
        unsigned short* yrow = yb + (jr << 10);

        float ixa[4], iya[4];
        bool bad = false;
#pragma unroll
        for (int q = 0; q < 4; ++q) {
            int I = (q << 8) + tid;
            float xv = fmaf((float)I, SSTEP, -1.0f);
            float dx = xv - x0;
            float s  = bpar * __builtin_amdgcn_rsqf(fmaf(dx, dx, dyt));
            float gx = xv - dx * s + sub0;
            float gy = yv - dy * s + sub1;
            ixa[q] = (gx + 1.0f) * (0.5f * 1023.0f);
            iya[q] = (gy + 1.0f) * (0.5f * 1023.0f);
            bad |= !(ixa[q] >= 0.f && ixa[q] < 1023.f &&
                     iya[q] >= 0.f && iya[q] < 1023.f);
        }
        if (!__any(bad)) {
            // fast: all 16 corner loads issued in one straight-line block
            float v00[4], v01[4], v10[4], v11[4], fxs[4], fys[4];
#pragma unroll
            for (int q = 0; q < 4; ++q) {
                float fx = floorf(ixa[q]), fy = floorf(iya[q]);
                fxs[q] = fx; fys[q] = fy;
                const float* p = sb + (((int)fy) << 10) + (int)fx;
                v00[q] = p[0];
                v01[q] = p[1];
                v10[q] = p[WW];
                v11[q] = p[WW + 1];
            }
#pragma unroll
            for (int q = 0; q < 4; ++q) {
                float wx1 = ixa[q] - fxs[q];
                float wy1 = iya[q] - fys[q];
                float wx0 = 1.f - wx1;
                float r0 = fmaf(wx1, v01[q], wx0 * v00[q]);
                float r1 = fmaf(wx1, v11[q], wx0 * v10[q]);
                float val = fmaf(wy1, r1, (1.f - wy1) * r0);
                yrow[(q << 8) + tid] = f2bf(val);
            }
        } else {
#pragma unroll
            for (int q = 0; q < 4; ++q) {
                int I = (q << 8) + tid;
                float val = warp_sample(sb, I, J, bpar, rc2, sub0, sub1, x0, y0);
                yrow[(q << 8) + tid] = f2bf(val);
            }
        }
    }
}

// ---------------- split kernel 2: stage bf16 tile (no warp math) -> MFMA conv -
__global__ __launch_bounds__(256, 4) void conv_kernel(
        const unsigned short* __restrict__ yw, const float* __restrict__ pp,
        float* __restrict__ out) {
    __shared__ unsigned short ThT[HALO_J * PITCH_T];   // [hc][hr'], 30.8KB

    const int tid = threadIdx.x;
    const int j0 = blockIdx.x * TJ;
    const int i0 = blockIdx.y * TI;
    const int b0 = blockIdx.z;

    const unsigned short* wb = yw + ((size_t)b0 << 20);

    // ---- staging: 148 rows x 12 chunks = 1776 16B loads, zero-fill OOB ----
    for (int p = tid; p < HALO_J * 12; p += 256) {
        int hc = (int)((unsigned)p / 12u);
        int c  = p - hc * 12;
        int J  = j0 - 10 + hc;
        int xs = i0 - 16 + c * 8;
        short8 d8 = {0, 0, 0, 0, 0, 0, 0, 0};
        if ((unsigned)J < HH && (unsigned)xs < WW)
            d8 = *(const short8*)&wb[J * WW + xs];
        *(short8*)&ThT[hc * PITCH_T + c * 8] = d8;
    }
    __syncthreads();

    // ---- MFMA conv with one-iteration A-fragment register prefetch ----
    const int lane = tid & 63;
    const int wv = tid >> 6;
    const int nrow = lane & 31;
    const int khalf = lane >> 5;

    float16 acc[2];
#pragma unroll
    for (int m = 0; m < 2; ++m)
#pragma unroll
        for (int q = 0; q < 16; ++q) acc[m][q] = 0.f;

    const short8* Ap = ((const short8*)(pp + AOFF2)) + lane;
    short8 AfN[4];
#pragma unroll
    for (int d = 0; d < 4; ++d)
        AfN[d] = Ap[d * 64];

#pragma unroll 1
    for (int v = 0; v < 21; ++v) {
        short8 Af[4];
#pragma unroll
        for (int d = 0; d < 4; ++d) Af[d] = AfN[d];
        // prefetch v+1 (v=20 reads 4KB past table end -> still inside ws, discarded)
#pragma unroll
        for (int d = 0; d < 4; ++d) AfN[d] = Ap[(v + 1) * 256 + d * 64];

        const unsigned short* bp = &ThT[(32 * wv + nrow + v) * PITCH_T + khalf * 8];
        short8 Bf[6];
#pragma unroll
        for (int c = 0; c < 6; ++c)
            Bf[c] = *(const short8*)&bp[16 * c];

#pragma unroll
        for (int mq = 0; mq < 2; ++mq) {
#pragma unroll
            for (int d = 0; d < 4; ++d)
                acc[mq] = __builtin_amdgcn_mfma_f32_32x32x16_bf16(
                    Af[d], Bf[2 * mq + d], acc[mq], 0, 0, 0);
        }
    }

    float* ob = out + (size_t)b0 * (WW * (size_t)HH);
    const int gj = j0 + 32 * wv + nrow;
#pragma unroll
    for (int mq = 0; mq < 2; ++mq) {
#pragma unroll
        for (int reg = 0; reg < 16; ++reg) {
            int row = (reg & 3) + 8 * (reg >> 2) + 4 * khalf;
            int gi = i0 + 32 * mq + row;
            ob[(size_t)gi * HH + gj] = acc[mq][reg];
        }
    }
}

// ---------------- fallback: round-4 fused kernel (used if ws too small) ------
__global__ __launch_bounds__(256, 4) void fused_kernel(
        const float* __restrict__ src, const float* __restrict__ pp,
        float* __restrict__ out) {
    __shared__ unsigned short ThT[HALO_J * PITCH_T];

    const int tid = threadIdx.x;
    const int j0 = blockIdx.x * TJ;
    const int i0 = blockIdx.y * TI;
    const int b0 = blockIdx.z;

    const float bpar = pp[441], rc2 = pp[442];
    const float sub0 = pp[443], sub1 = pp[444];
    const float x0 = pp[445], y0 = pp[446];

    const float* sb = src + (size_t)b0 * (HH * (size_t)WW);

    const int NELEM = HALO_J * FILL_I;
#pragma unroll 1
    for (int base = 0; base < NELEM; base += 1024) {
        float vals[4];
        int offs[4];
#pragma unroll
        for (int e = 0; e < 4; ++e) {
            int n = base + (e << 8) + tid;
            float val = 0.f;
            int off = -1;
            if (n < NELEM) {
                int hc = (int)((unsigned)n / 96u);
                int hr = n - hc * 96;
                off = hc * PITCH_T + hr;
                int J = j0 - 10 + hc;
                int I = i0 - 10 + hr;
                if (hr < VALID_I && (unsigned)J < HH && (unsigned)I < WW)
                    val = warp_sample(sb, I, J, bpar, rc2, sub0, sub1, x0, y0);
            }
            vals[e] = val;
            offs[e] = off;
        }
#pragma unroll
        for (int e = 0; e < 4; ++e) {
            if (offs[e] >= 0) ThT[offs[e]] = f2bf(vals[e]);
        }
    }
    __syncthreads();

    const int lane = tid & 63;
    const int wv = tid >> 6;
    const int nrow = lane & 31;
    const int khalf = lane >> 5;

    float16 acc[2];
#pragma unroll
    for (int m = 0; m < 2; ++m)
#pragma unroll
        for (int q = 0; q < 16; ++q) acc[m][q] = 0.f;

    const short8* Aall = (const short8*)(pp + AOFF);

#pragma unroll 1
    for (int v = 0; v < 21; ++v) {
        short8 Af[4];
#pragma unroll
        for (int d = 0; d < 4; ++d)
            Af[d] = Aall[(v * 4 + d) * 64 + lane];

        const unsigned short* bp = &ThT[(32 * wv + nrow + v) * PITCH_T + khalf * 8];
        short8 Bf[6];
#pragma unroll
        for (int c = 0; c < 6; ++c)
            Bf[c] = *(const short8*)&bp[16 * c];

#pragma unroll
        for (int mq = 0; mq < 2; ++mq) {
#pragma unroll
            for (int d = 0; d < 4; ++d)
                acc[mq] = __builtin_amdgcn_mfma_f32_32x32x16_bf16(
                    Af[d], Bf[2 * mq + d], acc[mq], 0, 0, 0);
        }
    }

    float* ob = out + (size_t)b0 * (WW * (size_t)HH);
    const int gj = j0 + 32 * wv + nrow;
#pragma unroll
    for (int mq = 0; mq < 2; ++mq) {
#pragma unroll
        for (int reg = 0; reg < 16; ++reg) {
            int row = (reg & 3) + 8 * (reg >> 2) + 4 * khalf;
            int gi = i0 + 32 * mq + row;
            ob[(size_t)gi * HH + gj] = acc[mq][reg];
        }
    }
}

extern "C" void kernel_launch(void* const* d_in, const int* in_sizes, int n_in,
                              void* d_out, int out_size, void* d_ws, size_t ws_size,
                              hipStream_t stream) {
    const float* src     = (const float*)d_in[0];
    const float* raw_psf = (const float*)d_in[1];
    const float* x0      = (const float*)d_in[2];
    const float* y0      = (const float*)d_in[3];
    const float* raw_b   = (const float*)d_in[4];
    const float* raw_rc  = (const float*)d_in[5];
    const float* raw_sub = (const float*)d_in[6];
    float* ws = (float*)d_ws;

    prep_kernel<<<1, 512, 0, stream>>>(raw_psf, x0, y0, raw_b, raw_rc, raw_sub, ws);

    dim3 grid(HH / TJ, WW / TI, 16);   // (8, 16, 16) = 2048 blocks
    if (ws_size >= (size_t)NEED_WS) {
        unsigned short* yw = (unsigned short*)(ws + YOFF);
        warp_kernel<<<2048, 256, 0, stream>>>(src, ws, yw);
        conv_kernel<<<grid, 256, 0, stream>>>(yw, ws, (float*)d_out);
    } else {
        fused_kernel<<<grid, 256, 0, stream>>>(src, ws, (float*)d_out);
    }
}

// Round 7
// 191.020 us; speedup vs baseline: 1.3851x; 1.1014x over previous
//
#include <hip/hip_runtime.h>
#include <math.h>

#define WW 1024
#define HH 1024
#define TI 64          // output tile extent in i (x)
#define TJ 128         // output tile extent in j (y)
#define HALO_J 148     // hc (y) extent = TJ + 20
#define VALID_I 84     // valid hr extent for fallback fused kernel
#define FILL_I 96      // fallback fill extent
#define PITCH_T 104    // ThT row pitch in elems; 208B, 52 dwords == 20 mod 32 (conflict-free)
#define AOFF 448       // float offset of A-pattern table (origin i0-10, fallback)
#define AOFF2 21952    // float offset of shifted A-pattern table (origin i0-16, split path)
#define YOFF 43520     // float offset of bf16 warped image (32MB)
#define NEED_WS (174080u + 33554432u)

typedef short short8 __attribute__((ext_vector_type(8)));
typedef float float16 __attribute__((ext_vector_type(16)));

__device__ __forceinline__ unsigned short f2bf(float f) {
    union { float f; unsigned int u; } c; c.f = f;
    unsigned int u = c.u;
    return (unsigned short)((u + 0x7FFFu + ((u >> 16) & 1u)) >> 16);
}

// warped-image sample at integer grid (I, J); val=0 outside image (conv zero-pad)
__device__ __forceinline__ float warp_sample(const float* __restrict__ sb, int I, int J,
                                             float bpar, float rc2, float sub0, float sub1,
                                             float x0, float y0) {
    const float SSTEP = 2.0f / 1023.0f;
    float yv = fmaf((float)J, SSTEP, -1.0f);
    float xv = fmaf((float)I, SSTEP, -1.0f);
    float dx = xv - x0;
    float dy = yv - y0;
    float s = bpar * __builtin_amdgcn_rsqf(dx * dx + dy * dy + rc2);
    float gx = xv - dx * s + sub0;
    float gy = yv - dy * s + sub1;
    float ix = (gx + 1.0f) * (0.5f * 1023.0f);
    float iy = (gy + 1.0f) * (0.5f * 1023.0f);
    float fx = floorf(ix), fy = floorf(iy);
    float wx1 = ix - fx, wy1 = iy - fy;
    float wx0 = 1.f - wx1, wy0 = 1.f - wy1;
    int xi0 = (int)fx, yi0 = (int)fy;
    int xi1 = xi0 + 1, yi1 = yi0 + 1;
    int xc0 = min(max(xi0, 0), WW - 1);
    int xc1 = min(max(xi1, 0), WW - 1);
    int yc0 = min(max(yi0, 0), HH - 1);
    int yc1 = min(max(yi1, 0), HH - 1);
    bool vx0 = (unsigned)xi0 < WW, vx1 = (unsigned)xi1 < WW;
    bool vy0 = (unsigned)yi0 < HH, vy1 = (unsigned)yi1 < HH;
    float w00 = (vx0 && vy0) ? wy0 * wx0 : 0.f;
    float w01 = (vx1 && vy0) ? wy0 * wx1 : 0.f;
    float w10 = (vx0 && vy1) ? wy1 * wx0 : 0.f;
    float w11 = (vx1 && vy1) ? wy1 * wx1 : 0.f;
    float v00 = sb[yc0 * WW + xc0];
    float v01 = sb[yc0 * WW + xc1];
    float v10 = sb[yc1 * WW + xc0];
    float v11 = sb[yc1 * WW + xc1];
    return v00 * w00 + v01 * w01 + v10 * w10 + v11 * w11;
}

// ---------------- prep: PSF normalize, params, both Toeplitz A-pattern tables
__global__ void prep_kernel(const float* __restrict__ raw_psf,
                            const float* __restrict__ x0p, const float* __restrict__ y0p,
                            const float* __restrict__ raw_b, const float* __restrict__ raw_rc,
                            const float* __restrict__ raw_sub,
                            float* __restrict__ ws) {
    __shared__ float red[512];
    __shared__ float psn[441];
    int t = threadIdx.x;
    float v = 0.f;
    if (t < 441) v = fmaxf(raw_psf[t], 0.f);
    red[t] = v;
    __syncthreads();
    for (int s = 256; s > 0; s >>= 1) {
        if (t < s) red[t] += red[t + s];
        __syncthreads();
    }
    float sum = fmaxf(red[0], 1e-12f);
    if (t < 441) { float pn = v / sum; ws[t] = pn; psn[t] = pn; }
    if (t == 0) {
        float b  = log1pf(expf(raw_b[0]))  + 1e-8f;
        float rc = log1pf(expf(raw_rc[0])) + 1e-8f;
        ws[441] = b;
        ws[442] = 1e-12f + rc * rc;
        ws[443] = 0.25f * tanhf(raw_sub[0]);
        ws[444] = 0.25f * tanhf(raw_sub[1]);
        ws[445] = x0p[0];
        ws[446] = y0p[0];
    }
    __syncthreads();

    short* A  = (short*)(ws + AOFF);
    short* A2 = (short*)(ws + AOFF2);
    for (int g = t; g < 21 * 256; g += 512) {      // g = v*256 + d*64 + l
        int vv = g >> 8;
        int r  = g & 255;
        int d  = r >> 6;
        int l  = r & 63;
        int m  = l & 31;
        int k0 = (l >> 5) << 3;
        short8 o8, o8b;
#pragma unroll
        for (int q = 0; q < 8; ++q) {
            int u = 16 * d + k0 + q - m;
            unsigned short pv = 0, pv2 = 0;
            if ((unsigned)u <= 20u) pv = f2bf(psn[u * 21 + vv]);
            int u2 = u - 6;
            if ((unsigned)u2 <= 20u) pv2 = f2bf(psn[u2 * 21 + vv]);
            o8[q]  = (short)pv;
            o8b[q] = (short)pv2;
        }
        *(short8*)&A[(size_t)g * 8]  = o8;
        *(short8*)&A2[(size_t)g * 8] = o8b;
    }
}

// ---------------- split kernel 1: warp each pixel EXACTLY ONCE -> bf16 image --
__global__ __launch_bounds__(256, 4) void warp_kernel(
        const float* __restrict__ src, const float* __restrict__ pp,
        unsigned short* __restrict__ yw) {
    const float bpar = pp[441], rc2 = pp[442];
    const float sub0 = pp[443], sub1 = pp[444];
    const float x0 = pp[445], y0 = pp[446];
    const float SSTEP = 2.0f / 1023.0f;

    const int tid = threadIdx.x;
    const int nb  = blockIdx.x;            // 2048 blocks = 16 images x 128
    const int b0  = nb >> 7;
    const int J0  = (nb & 127) << 3;       // 8 rows per block
    const float* sb = src + ((size_t)b0 << 20);
    unsigned short* yb = yw + ((size_t)b0 << 20) + ((size_t)J0 << 10);

#pragma unroll 1
    for (int jr = 0; jr < 8; ++jr) {
        int J = J0 + jr;
        float yv = fmaf((float)J, SSTEP, -1.0f);
        float dy = yv - y0;
        float dyt = fmaf(dy, dy, rc2);
        unsigned short* yrow = yb + (jr << 10);

        float ixa[4], iya[4];
        bool bad = false;
#pragma unroll
        for (int q = 0; q < 4; ++q) {
            int I = (q << 8) + tid;
            float xv = fmaf((float)I, SSTEP, -1.0f);
            float dx = xv - x0;
            float s  = bpar * __builtin_amdgcn_rsqf(fmaf(dx, dx, dyt));
            float gx = xv - dx * s + sub0;
            float gy = yv - dy * s + sub1;
            ixa[q] = (gx + 1.0f) * (0.5f * 1023.0f);
            iya[q] = (gy + 1.0f) * (0.5f * 1023.0f);
            bad |= !(ixa[q] >= 0.f && ixa[q] < 1023.f &&
                     iya[q] >= 0.f && iya[q] < 1023.f);
        }
        if (!__any(bad)) {
            // fast: all 16 corner loads issued in one straight-line block
            float v00[4], v01[4], v10[4], v11[4], fxs[4], fys[4];
#pragma unroll
            for (int q = 0; q < 4; ++q) {
                float fx = floorf(ixa[q]), fy = floorf(iya[q]);
                fxs[q] = fx; fys[q] = fy;
                const float* p = sb + (((int)fy) << 10) + (int)fx;
                v00[q] = p[0];
                v01[q] = p[1];
                v10[q] = p[WW];
                v11[q] = p[WW + 1];
            }
#pragma unroll
            for (int q = 0; q < 4; ++q) {
                float wx1 = ixa[q] - fxs[q];
                float wy1 = iya[q] - fys[q];
                float wx0 = 1.f - wx1;
                float r0 = fmaf(wx1, v01[q], wx0 * v00[q]);
                float r1 = fmaf(wx1, v11[q], wx0 * v10[q]);
                float val = fmaf(wy1, r1, (1.f - wy1) * r0);
                yrow[(q << 8) + tid] = f2bf(val);
            }
        } else {
#pragma unroll
            for (int q = 0; q < 4; ++q) {
                int I = (q << 8) + tid;
                float val = warp_sample(sb, I, J, bpar, rc2, sub0, sub1, x0, y0);
                yrow[(q << 8) + tid] = f2bf(val);
            }
        }
    }
}

// ---------------- split kernel 2: stage bf16 tile (no warp math) -> MFMA conv -
// 5 blocks/CU (LDS 5x31.5KB = 157.5KB); depth-2 A prefetch (ping-pong AfA/AfB).
__global__ __launch_bounds__(256, 5) void conv_kernel(
        const unsigned short* __restrict__ yw, const float* __restrict__ pp,
        float* __restrict__ out) {
    __shared__ unsigned short ThT[HALO_J * PITCH_T];   // [hc][hr'], 30.8KB

    const int tid = threadIdx.x;
    const int j0 = blockIdx.x * TJ;
    const int i0 = blockIdx.y * TI;
    const int b0 = blockIdx.z;

    const int lane = tid & 63;
    const int wv = tid >> 6;
    const int nrow = lane & 31;
    const int khalf = lane >> 5;

    // issue A-loads for v=0,1 BEFORE staging so they land under the barrier
    const short8* Ap = ((const short8*)(pp + AOFF2)) + lane;
    short8 AfA[4], AfB[4];
#pragma unroll
    for (int d = 0; d < 4; ++d) AfA[d] = Ap[d * 64];
#pragma unroll
    for (int d = 0; d < 4; ++d) AfB[d] = Ap[256 + d * 64];

    const unsigned short* wb = yw + ((size_t)b0 << 20);

    // ---- staging: 148 rows x 12 chunks = 1776 16B loads, zero-fill OOB ----
    for (int p = tid; p < HALO_J * 12; p += 256) {
        int hc = (int)((unsigned)p / 12u);
        int c  = p - hc * 12;
        int J  = j0 - 10 + hc;
        int xs = i0 - 16 + c * 8;
        short8 d8 = {0, 0, 0, 0, 0, 0, 0, 0};
        if ((unsigned)J < HH && (unsigned)xs < WW)
            d8 = *(const short8*)&wb[J * WW + xs];
        *(short8*)&ThT[hc * PITCH_T + c * 8] = d8;
    }
    __syncthreads();

    float16 acc[2];
#pragma unroll
    for (int m = 0; m < 2; ++m)
#pragma unroll
        for (int q = 0; q < 16; ++q) acc[m][q] = 0.f;

    const unsigned short* bpbase = &ThT[(32 * wv + nrow) * PITCH_T + khalf * 8];

    // ---- v-loop unrolled x2: consume AfA/AfB, prefetch v+2/v+3 (2-iter slack) --
#pragma unroll 1
    for (int v = 0; v < 20; v += 2) {
        {   // even iter: consume AfA, prefetch v+2 (<=20, no clamp needed)
            short8 Cur[4];
#pragma unroll
            for (int d = 0; d < 4; ++d) Cur[d] = AfA[d];
            int vp = v + 2;
#pragma unroll
            for (int d = 0; d < 4; ++d) AfA[d] = Ap[vp * 256 + d * 64];

            const unsigned short* bp = bpbase + v * PITCH_T;
            short8 Bf[6];
#pragma unroll
            for (int c = 0; c < 6; ++c) Bf[c] = *(const short8*)&bp[16 * c];
#pragma unroll
            for (int mq = 0; mq < 2; ++mq)
#pragma unroll
                for (int d = 0; d < 4; ++d)
                    acc[mq] = __builtin_amdgcn_mfma_f32_32x32x16_bf16(
                        Cur[d], Bf[2 * mq + d], acc[mq], 0, 0, 0);
        }
        {   // odd iter: consume AfB, prefetch v+3 (clamped; v=18 wastes 4 loads)
            short8 Cur[4];
#pragma unroll
            for (int d = 0; d < 4; ++d) Cur[d] = AfB[d];
            int vp = v + 3; vp = vp > 20 ? 20 : vp;
#pragma unroll
            for (int d = 0; d < 4; ++d) AfB[d] = Ap[vp * 256 + d * 64];

            const unsigned short* bp = bpbase + (v + 1) * PITCH_T;
            short8 Bf[6];
#pragma unroll
            for (int c = 0; c < 6; ++c) Bf[c] = *(const short8*)&bp[16 * c];
#pragma unroll
            for (int mq = 0; mq < 2; ++mq)
#pragma unroll
                for (int d = 0; d < 4; ++d)
                    acc[mq] = __builtin_amdgcn_mfma_f32_32x32x16_bf16(
                        Cur[d], Bf[2 * mq + d], acc[mq], 0, 0, 0);
        }
    }
    {   // final v=20: AfA holds v=20 (prefetched at v=18)
        const unsigned short* bp = bpbase + 20 * PITCH_T;
        short8 Bf[6];
#pragma unroll
        for (int c = 0; c < 6; ++c) Bf[c] = *(const short8*)&bp[16 * c];
#pragma unroll
        for (int mq = 0; mq < 2; ++mq)
#pragma unroll
            for (int d = 0; d < 4; ++d)
                acc[mq] = __builtin_amdgcn_mfma_f32_32x32x16_bf16(
                    AfA[d], Bf[2 * mq + d], acc[mq], 0, 0, 0);
    }

    float* ob = out + (size_t)b0 * (WW * (size_t)HH);
    const int gj = j0 + 32 * wv + nrow;
#pragma unroll
    for (int mq = 0; mq < 2; ++mq) {
#pragma unroll
        for (int reg = 0; reg < 16; ++reg) {
            int row = (reg & 3) + 8 * (reg >> 2) + 4 * khalf;
            int gi = i0 + 32 * mq + row;
            ob[(size_t)gi * HH + gj] = acc[mq][reg];
        }
    }
}

// ---------------- fallback: round-4 fused kernel (used if ws too small) ------
__global__ __launch_bounds__(256, 4) void fused_kernel(
        const float* __restrict__ src, const float* __restrict__ pp,
        float* __restrict__ out) {
    __shared__ unsigned short ThT[HALO_J * PITCH_T];

    const int tid = threadIdx.x;
    const int j0 = blockIdx.x * TJ;
    const int i0 = blockIdx.y * TI;
    const int b0 = blockIdx.z;

    const float bpar = pp[441], rc2 = pp[442];
    const float sub0 = pp[443], sub1 = pp[444];
    const float x0 = pp[445], y0 = pp[446];

    const float* sb = src + (size_t)b0 * (HH * (size_t)WW);

    const int NELEM = HALO_J * FILL_I;
#pragma unroll 1
    for (int base = 0; base < NELEM; base += 1024) {
        float vals[4];
        int offs[4];
#pragma unroll
        for (int e = 0; e < 4; ++e) {
            int n = base + (e << 8) + tid;
            float val = 0.f;
            int off = -1;
            if (n < NELEM) {
                int hc = (int)((unsigned)n / 96u);
                int hr = n - hc * 96;
                off = hc * PITCH_T + hr;
                int J = j0 - 10 + hc;
                int I = i0 - 10 + hr;
                if (hr < VALID_I && (unsigned)J < HH && (unsigned)I < WW)
                    val = warp_sample(sb, I, J, bpar, rc2, sub0, sub1, x0, y0);
            }
            vals[e] = val;
            offs[e] = off;
        }
#pragma unroll
        for (int e = 0; e < 4; ++e) {
            if (offs[e] >= 0) ThT[offs[e]] = f2bf(vals[e]);
        }
    }
    __syncthreads();

    const int lane = tid & 63;
    const int wv = tid >> 6;
    const int nrow = lane & 31;
    const int khalf = lane >> 5;

    float16 acc[2];
#pragma unroll
    for (int m = 0; m < 2; ++m)
#pragma unroll
        for (int q = 0; q < 16; ++q) acc[m][q] = 0.f;

    const short8* Aall = (const short8*)(pp + AOFF);

#pragma unroll 1
    for (int v = 0; v < 21; ++v) {
        short8 Af[4];
#pragma unroll
        for (int d = 0; d < 4; ++d)
            Af[d] = Aall[(v * 4 + d) * 64 + lane];

        const unsigned short* bp = &ThT[(32 * wv + nrow + v) * PITCH_T + khalf * 8];
        short8 Bf[6];
#pragma unroll
        for (int c = 0; c < 6; ++c)
            Bf[c] = *(const short8*)&bp[16 * c];

#pragma unroll
        for (int mq = 0; mq < 2; ++mq) {
#pragma unroll
            for (int d = 0; d < 4; ++d)
                acc[mq] = __builtin_amdgcn_mfma_f32_32x32x16_bf16(
                    Af[d], Bf[2 * mq + d], acc[mq], 0, 0, 0);
        }
    }

    float* ob = out + (size_t)b0 * (WW * (size_t)HH);
    const int gj = j0 + 32 * wv + nrow;
#pragma unroll
    for (int mq = 0; mq < 2; ++mq) {
#pragma unroll
        for (int reg = 0; reg < 16; ++reg) {
            int row = (reg & 3) + 8 * (reg >> 2) + 4 * khalf;
            int gi = i0 + 32 * mq + row;
            ob[(size_t)gi * HH + gj] = acc[mq][reg];
        }
    }
}

extern "C" void kernel_launch(void* const* d_in, const int* in_sizes, int n_in,
                              void* d_out, int out_size, void* d_ws, size_t ws_size,
                              hipStream_t stream) {
    const float* src     = (const float*)d_in[0];
    const float* raw_psf = (const float*)d_in[1];
    const float* x0      = (const float*)d_in[2];
    const float* y0      = (const float*)d_in[3];
    const float* raw_b   = (const float*)d_in[4];
    const float* raw_rc  = (const float*)d_in[5];
    const float* raw_sub = (const float*)d_in[6];
    float* ws = (float*)d_ws;

    prep_kernel<<<1, 512, 0, stream>>>(raw_psf, x0, y0, raw_b, raw_rc, raw_sub, ws);

    dim3 grid(HH / TJ, WW / TI, 16);   // (8, 16, 16) = 2048 blocks
    if (ws_size >= (size_t)NEED_WS) {
        unsigned short* yw = (unsigned short*)(ws + YOFF);
        warp_kernel<<<2048, 256, 0, stream>>>(src, ws, yw);
        conv_kernel<<<grid, 256, 0, stream>>>(yw, ws, (float*)d_out);
    } else {
        fused_kernel<<<grid, 256, 0, stream>>>(src, ws, (float*)d_out);
    }
}